// Round 1
// baseline (8205.922 us; speedup 1.0000x reference)
//
#include <hip/hip_runtime.h>

#define BB 256     // batch
#define MM 256     // constraints
#define VV 1024    // vars
#define KCAP 576   // reserve for masked-coordinate count (mean 512, +4 sigma)
#define KROWS 640  // per-batch padded vector length for loop-state buffers
#define NITERS 100
#define EPSJ 1e-6f
#define LTOT 33280 // quad-padded packed lower-triangular floats per batch

// ---------------- workspace layout (bytes) ----------------
static const size_t CT_OFF   = 0ull;
static const size_t CT_BYTES = (size_t)BB*KCAP*MM*4;     // C^T = (L^{-1} A_K)^T, [B][K][M]
static const size_t G_OFF    = CT_OFF + CT_BYTES;
static const size_t G_BYTES  = (size_t)BB*KCAP*KCAP*4;   // G = 0.5*C^T C, [B][KP][KP]
static const size_t S_OFF    = G_OFF;                    // S overlays G region (dead before G written)
static const size_t L_OFF    = G_OFF + G_BYTES;
static const size_t L_BYTES  = (size_t)BB*LTOT*4;
static const size_t DI_OFF   = L_OFF + L_BYTES;          // Dinv: 16x 16x16 diag-block inverses / batch
static const size_t DI_BYTES = (size_t)BB*16*16*16*4;
static const size_t IDX_OFF  = DI_OFF + DI_BYTES;
static const size_t POS_OFF  = IDX_OFF + 4096;
static const size_t KD_OFF   = POS_OFF + 4096;
static const size_t AX_OFF   = KD_OFF + 256;
static const size_t H_OFF    = AX_OFF + (size_t)BB*MM*4;
static const size_t BE_OFF   = H_OFF  + (size_t)BB*MM*4;
static const size_t PS_OFF   = BE_OFF + (size_t)BB*MM*4;
static const size_t EH_OFF   = PS_OFF + (size_t)BB*MM*4;
static const size_t EB_OFF   = EH_OFF + (size_t)BB*VV*4;
static const size_t BASE_OFF = EB_OFF + (size_t)BB*VV*4;
static const size_t P0_OFF   = BASE_OFF + (size_t)BB*KROWS*4;
static const size_t P1_OFF   = P0_OFF + (size_t)BB*KROWS*4;
static const size_t P2_OFF   = P1_OFF + (size_t)BB*KROWS*4;
static const size_t DA_OFF   = P2_OFF + (size_t)BB*KROWS*4;
static const size_t WS_NEED  = DA_OFF + (size_t)BB*KROWS*4;  // ~510.6 MiB

// quad-padded packed-lower row offset: row i starts at lpad(i), length ceil((i+1)/4)*4
__device__ __forceinline__ int lpad(int i){ int q = i >> 2, r = i & 3; return 8*q*(q+1) + 4*r*(q+1); }

// ---------------- K0: mask scan -> idx, pos, K ----------------
__global__ void k_scan(const int* __restrict__ mask, int* __restrict__ idx,
                       int* __restrict__ pos, int* __restrict__ Kd){
  __shared__ int ps[VV];
  int t = threadIdx.x;
  int mv = mask[t] > 0 ? 1 : 0;
  ps[t] = mv;
  __syncthreads();
  for (int off = 1; off < VV; off <<= 1){
    int add = (t >= off) ? ps[t - off] : 0;
    __syncthreads();
    ps[t] += add;
    __syncthreads();
  }
  int incl = ps[t];
  int excl = incl - mv;
  if (mv){ if (excl < KCAP) idx[excl] = t; pos[t] = excl; }
  else pos[t] = -1;
  if (t == VV-1){ int K = incl; if (K > KCAP) K = KCAP; Kd[0] = K; }
}

// ---------------- ax = A x ----------------
__global__ __launch_bounds__(256) void k_ax(const float* __restrict__ A, const float* __restrict__ x,
                                            float* __restrict__ ax){
  int b = blockIdx.x, t = threadIdx.x;
  __shared__ __align__(16) float xs[VV];
  for (int v = t; v < VV; v += 256) xs[v] = x[(size_t)b*VV + v];
  __syncthreads();
  int lane = t & 63, wv = t >> 6;
  const float* Ab = A + (size_t)b*MM*VV;
  const float4* xv4 = (const float4*)xs;
  for (int m = wv; m < MM; m += 4){
    const float4* row = (const float4*)(Ab + (size_t)m*VV);
    float acc = 0.f;
    for (int j = lane; j < VV/4; j += 64){
      float4 a = row[j], xv = xv4[j];
      acc += a.x*xv.x + a.y*xv.y + a.z*xv.z + a.w*xv.w;
    }
    for (int s = 32; s; s >>= 1) acc += __shfl_xor(acc, s);
    if (lane == 0) ax[b*MM + m] = acc;
  }
}

// ---------------- S = A A^T + eps I (symmetric, 64x64 lower tiles) ----------------
__global__ __launch_bounds__(256) void k_aat(const float* __restrict__ A, float* __restrict__ S){
  int blk = blockIdx.x;
  int b = blk / 10, p = blk % 10;
  int ti = 0, acc0 = 0;
  while (acc0 + ti + 1 <= p){ acc0 += ti + 1; ti++; }
  int tj = p - acc0;
  int i0 = ti*64, j0 = tj*64;
  __shared__ __align__(16) float As[16][68];
  __shared__ __align__(16) float Bs[16][68];
  int t = threadIdx.x;
  int lr = t >> 2;
  int lk = (t & 3) * 4;
  int ty = t >> 4, tx = t & 15;
  const float* Ab = A + (size_t)b*MM*VV;
  float acc[4][4] = {};
  for (int k0 = 0; k0 < VV; k0 += 16){
    float4 av = *(const float4*)(Ab + (size_t)(i0+lr)*VV + k0 + lk);
    float4 bv = *(const float4*)(Ab + (size_t)(j0+lr)*VV + k0 + lk);
    __syncthreads();
    As[lk+0][lr] = av.x; As[lk+1][lr] = av.y; As[lk+2][lr] = av.z; As[lk+3][lr] = av.w;
    Bs[lk+0][lr] = bv.x; Bs[lk+1][lr] = bv.y; Bs[lk+2][lr] = bv.z; Bs[lk+3][lr] = bv.w;
    __syncthreads();
    #pragma unroll
    for (int kk = 0; kk < 16; kk++){
      float4 a4 = *(const float4*)&As[kk][ty*4];
      float4 b4 = *(const float4*)&Bs[kk][tx*4];
      acc[0][0] += a4.x*b4.x; acc[0][1] += a4.x*b4.y; acc[0][2] += a4.x*b4.z; acc[0][3] += a4.x*b4.w;
      acc[1][0] += a4.y*b4.x; acc[1][1] += a4.y*b4.y; acc[1][2] += a4.y*b4.z; acc[1][3] += a4.y*b4.w;
      acc[2][0] += a4.z*b4.x; acc[2][1] += a4.z*b4.y; acc[2][2] += a4.z*b4.z; acc[2][3] += a4.z*b4.w;
      acc[3][0] += a4.w*b4.x; acc[3][1] += a4.w*b4.y; acc[3][2] += a4.w*b4.z; acc[3][3] += a4.w*b4.w;
    }
  }
  float* Sb = S + (size_t)b*MM*MM;
  #pragma unroll
  for (int ii = 0; ii < 4; ii++)
  #pragma unroll
  for (int jj = 0; jj < 4; jj++){
    int i = i0 + ty*4 + ii, j = j0 + tx*4 + jj;
    float v = acc[ii][jj] + (i == j ? EPSJ : 0.f);
    Sb[(size_t)i*MM + j] = v;
    if (i0 != j0) Sb[(size_t)j*MM + i] = v;
  }
}

// ---------------- per-batch blocked Cholesky in LDS (packed, quad-padded rows) ----------------
__global__ __launch_bounds__(256) void k_chol(const float* __restrict__ S, float* __restrict__ Lg){
  __shared__ float Lp[LTOT];   // 133,120 B
  __shared__ float bc;
  int b = blockIdx.x, t = threadIdx.x;
  const float* Sb = S + (size_t)b*MM*MM;
  {
    int base = lpad(t);
    for (int j = 0; j <= t; j++) Lp[base + j] = Sb[(size_t)t*MM + j];
  }
  __syncthreads();
  for (int pb = 0; pb < 16; pb++){
    int p0 = pb*16;
    // panel factorization (cols p0..p0+15); prior-panel contributions already applied (right-looking)
    for (int c = 0; c < 16; c++){
      int j = p0 + c;
      float a = 0.f;
      if (t >= j){
        a = Lp[lpad(t) + j];
        int rb = lpad(t) + p0, jb = lpad(j) + p0;
        for (int cc = 0; cc < c; cc++) a -= Lp[rb + cc] * Lp[jb + cc];
      }
      if (t == j) bc = sqrtf(fmaxf(a, 1e-30f));
      __syncthreads();
      float d = bc;
      if (t == j) Lp[lpad(j) + j] = d;
      else if (t > j) Lp[lpad(t) + j] = a / d;
      __syncthreads();
    }
    int pe = p0 + 16;
    if (pe < MM){
      // rank-16 trailing update, 4x4 register tiles (diag-tile overwrites land in pad slots: harmless)
      for (int l = t; l < 4096; l += 256){
        int ti4 = l >> 6, tk4 = l & 63;
        if (tk4 > ti4) continue;
        int i0 = ti4*4, k0 = tk4*4;
        if (k0 < pe) continue;
        int qi = i0 >> 2, qk = k0 >> 2;
        int ibase = 8*qi*(qi+1), istr = 4*(qi+1);
        int kbase = 8*qk*(qk+1), kstr = 4*(qk+1);
        float acc2[4][4] = {};
        #pragma unroll
        for (int cq = 0; cq < 4; cq++){
          float4 ar[4], br[4];
          #pragma unroll
          for (int r = 0; r < 4; r++){
            ar[r] = *(const float4*)&Lp[ibase + r*istr + p0 + cq*4];
            br[r] = *(const float4*)&Lp[kbase + r*kstr + p0 + cq*4];
          }
          #pragma unroll
          for (int r = 0; r < 4; r++){
            #pragma unroll
            for (int s2 = 0; s2 < 4; s2++){
              acc2[r][s2] += ar[r].x*br[s2].x + ar[r].y*br[s2].y + ar[r].z*br[s2].z + ar[r].w*br[s2].w;
            }
          }
        }
        #pragma unroll
        for (int r = 0; r < 4; r++){
          float4* dst = (float4*)&Lp[ibase + r*istr + k0];
          float4 dv = *dst;
          dv.x -= acc2[r][0]; dv.y -= acc2[r][1]; dv.z -= acc2[r][2]; dv.w -= acc2[r][3];
          *dst = dv;
        }
      }
    }
    __syncthreads();
  }
  float* Lb = Lg + (size_t)b*LTOT;
  for (int l = t; l < LTOT; l += 256) Lb[l] = Lp[l];
}

// ---------------- Dinv: inverses of the 16 diagonal 16x16 triangular blocks ----------------
__global__ __launch_bounds__(256) void k_dinv(const float* __restrict__ Lg, float* __restrict__ Di){
  int b = blockIdx.x, t = threadIdx.x;
  int d = t >> 4, c = t & 15;
  const float* Lb = Lg + (size_t)b*LTOT;
  float x[16];
  #pragma unroll
  for (int i = 0; i < 16; i++) x[i] = 0.f;
  #pragma unroll
  for (int i = 0; i < 16; i++){
    const float* Lr = Lb + lpad(d*16 + i) + d*16;
    float s = (i == c) ? 1.f : 0.f;
    #pragma unroll
    for (int k = 0; k < 16; k++) if (k < i) s -= Lr[k] * x[k];
    float xi = (i >= c) ? (s / Lr[i]) : 0.f;
    x[i] = xi;
  }
  float* Db = Di + ((size_t)b*16 + d)*256;
  #pragma unroll
  for (int i = 0; i < 16; i++) Db[i*16 + c] = x[i];
}

// ---------------- blocked triangular solves (per-batch, vectors in LDS) ----------------
__device__ void solve_fwd(const float* Lb, const float* Db, const float* rin, float* yout,
                          float* u, float (*pp)[17], int t){
  int i = t & 15, kq = t >> 4;
  for (int ib = 0; ib < 16; ib++){
    float part = 0.f;
    for (int kb = 0; kb < ib; kb++){
      int k = kb*16 + kq;
      part += Lb[lpad(ib*16 + i) + k] * yout[k];
    }
    pp[i][kq] = part;
    __syncthreads();
    if (kq == 0){
      float s = rin[ib*16 + i];
      for (int q = 0; q < 16; q++) s -= pp[i][q];
      u[i] = s;
    }
    __syncthreads();
    if (kq == 0){
      float v = 0.f;
      const float* Dd = Db + ib*256 + i*16;
      for (int k = 0; k <= i; k++) v += Dd[k]*u[k];
      yout[ib*16 + i] = v;
    }
    __syncthreads();
  }
}

__device__ void solve_bwd(const float* Lb, const float* Db, const float* rin, float* yout,
                          float* u, float (*pp)[17], int t){
  int i = t & 15, kq = t >> 4;
  for (int ib = 15; ib >= 0; ib--){
    float part = 0.f;
    for (int kb = ib+1; kb < 16; kb++){
      int kg = kb*16 + kq;
      part += Lb[lpad(kg) + ib*16 + i] * yout[kg];
    }
    pp[i][kq] = part;
    __syncthreads();
    if (kq == 0){
      float s = rin[ib*16 + i];
      for (int q = 0; q < 16; q++) s -= pp[i][q];
      u[i] = s;
    }
    __syncthreads();
    if (kq == 0){
      float v = 0.f;
      const float* Dd = Db + ib*256;
      for (int k = i; k < 16; k++) v += Dd[k*16 + i] * u[k];
      yout[ib*16 + i] = v;
    }
    __syncthreads();
  }
}

// ---------------- h = S^{-1}(ax-2b)/2 ; axt = ax/2 - S h + eps h ; beta = S^{-1} axt ----------------
__global__ __launch_bounds__(256) void k_small(const float* __restrict__ Lg, const float* __restrict__ Di,
    const float* __restrict__ S, const float* __restrict__ ax, const float* __restrict__ bvec,
    float* __restrict__ hout, float* __restrict__ bout){
  __shared__ float r[MM], y[MM], hvec[MM], axt[MM], u[16], pp[16][17];
  int b = blockIdx.x, t = threadIdx.x;
  const float* Lb = Lg + (size_t)b*LTOT;
  const float* Db = Di + (size_t)b*4096;
  r[t] = ax[b*MM + t] - 2.f*bvec[b*MM + t];
  __syncthreads();
  solve_fwd(Lb, Db, r, y, u, pp, t);
  solve_bwd(Lb, Db, y, hvec, u, pp, t);
  hvec[t] *= 0.5f;
  __syncthreads();
  hout[b*MM + t] = hvec[t];
  float sh = 0.f;
  for (int j = 0; j < MM; j++) sh += S[((size_t)b*MM + j)*MM + t] * hvec[j];  // S symmetric: coalesced
  axt[t] = 0.5f*ax[b*MM + t] - sh + EPSJ*hvec[t];
  __syncthreads();
  solve_fwd(Lb, Db, axt, y, u, pp, t);
  solve_bwd(Lb, Db, y, r, u, pp, t);   // r := beta
  bout[b*MM + t] = r[t];
}

// ---------------- eh = A^T h, eb = A^T beta ----------------
__global__ __launch_bounds__(256) void k_e(const float* __restrict__ A, const float* __restrict__ h,
    const float* __restrict__ be, float* __restrict__ eh, float* __restrict__ eb){
  int b = blockIdx.x, t = threadIdx.x;
  __shared__ float hs[MM], bs[MM];
  hs[t] = h[b*MM + t]; bs[t] = be[b*MM + t];
  __syncthreads();
  const float* Ab = A + (size_t)b*MM*VV;
  float4 a1 = {0,0,0,0}, a2 = {0,0,0,0};
  for (int m = 0; m < MM; m++){
    float4 av = ((const float4*)(Ab + (size_t)m*VV))[t];
    float hm = hs[m], bm = bs[m];
    a1.x += av.x*hm; a1.y += av.y*hm; a1.z += av.z*hm; a1.w += av.w*hm;
    a2.x += av.x*bm; a2.y += av.y*bm; a2.z += av.z*bm; a2.w += av.w*bm;
  }
  ((float4*)(eh + (size_t)b*VV))[t] = a1;
  ((float4*)(eb + (size_t)b*VV))[t] = a2;
}

// ---------------- init: base = xt_K - 0.5*eb_K ; w0 = xt_K ; zero wprev(-1), D ----------------
__global__ __launch_bounds__(256) void k_init(const float* __restrict__ x, const float* __restrict__ eh,
    const float* __restrict__ eb, const int* __restrict__ idx, const int* __restrict__ Kd,
    float* __restrict__ base, float* __restrict__ P0, float* __restrict__ P2, float* __restrict__ Da){
  int K = Kd[0];
  int b = blockIdx.x, t = threadIdx.x;
  for (int j = t; j < K; j += 256){
    int c = idx[j];
    float xt = 0.5f*x[(size_t)b*VV + c] - eh[(size_t)b*VV + c];
    base[(size_t)b*KROWS + j] = xt - 0.5f*eb[(size_t)b*VV + c];
    P0[(size_t)b*KROWS + j]   = xt;
    P2[(size_t)b*KROWS + j]   = 0.f;
    Da[(size_t)b*KROWS + j]   = 0.f;
  }
}

// ---------------- C^T = (L^{-1} A_K)^T via chunked blocked forward substitution ----------------
__global__ __launch_bounds__(256) void k_solveC(const float* __restrict__ A, const float* __restrict__ Lg,
    const float* __restrict__ Di, const int* __restrict__ idx, const int* __restrict__ Kd,
    float* __restrict__ CT){
  int K = Kd[0];
  int ch = blockIdx.x, b = blockIdx.y;
  if (ch*32 >= K) return;
  __shared__ __align__(16) float Cl[32][256];      // col-major: Cl[c][row]
  __shared__ __align__(16) float Lpan[16*320];     // [kb][i(stride 20)][k]
  __shared__ float Dt[256];
  __shared__ int colv[32];
  int t = threadIdx.x;
  if (t < 32){ int j = ch*32 + t; colv[t] = (j < K) ? idx[j] : -1; }
  __syncthreads();
  int i = t & 15, cg = t >> 4;
  int c0 = cg*2, c1 = c0 + 1;
  const float* Lb = Lg + (size_t)b*LTOT;
  const float* Ab = A + (size_t)b*MM*VV;
  for (int ib = 0; ib < 16; ib++){
    for (int l = t; l < ib*256; l += 256){
      int kb = l >> 8, rem = l & 255;
      int ri = rem >> 4, k = rem & 15;
      Lpan[kb*320 + ri*20 + k] = Lb[lpad(ib*16 + ri) + kb*16 + k];
    }
    Dt[t] = Di[(size_t)b*4096 + ib*256 + t];
    __syncthreads();
    int gi = ib*16 + i;
    int col0 = colv[c0], col1 = colv[c1];
    float u0 = (col0 >= 0) ? Ab[(size_t)gi*VV + col0] : 0.f;
    float u1 = (col1 >= 0) ? Ab[(size_t)gi*VV + col1] : 0.f;
    for (int kb = 0; kb < ib; kb++){
      const float4* Lr = (const float4*)&Lpan[kb*320 + i*20];
      const float4* C0 = (const float4*)&Cl[c0][kb*16];
      const float4* C1 = (const float4*)&Cl[c1][kb*16];
      #pragma unroll
      for (int q = 0; q < 4; q++){
        float4 lv = Lr[q], cv0 = C0[q], cv1 = C1[q];
        u0 -= lv.x*cv0.x + lv.y*cv0.y + lv.z*cv0.z + lv.w*cv0.w;
        u1 -= lv.x*cv1.x + lv.y*cv1.y + lv.z*cv1.z + lv.w*cv1.w;
      }
    }
    Cl[c0][gi] = u0;
    Cl[c1][gi] = u1;
    __syncthreads();
    float x0 = 0.f, x1 = 0.f;
    #pragma unroll
    for (int k = 0; k < 16; k++){
      float dv = Dt[i*16 + k];            // zero for k > i
      x0 += dv * Cl[c0][ib*16 + k];
      x1 += dv * Cl[c1][ib*16 + k];
    }
    __syncthreads();
    Cl[c0][gi] = x0; Cl[c1][gi] = x1;
    int j0 = ch*32 + c0, j1 = ch*32 + c1;
    if (j0 < K) CT[((size_t)b*K + j0)*MM + gi] = x0;
    if (j1 < K) CT[((size_t)b*K + j1)*MM + gi] = x1;
    __syncthreads();
  }
}

// ---------------- G = 0.5 * C^T C (symmetric, 64x64 lower tiles over rows of CT) ----------------
__global__ __launch_bounds__(256) void k_gram(const float* __restrict__ CT, const int* __restrict__ Kd,
                                              float* __restrict__ G){
  int K = Kd[0];
  int KP = (K + 3) & ~3;
  int blk = blockIdx.x;
  int b = blk / 45, p = blk % 45;
  int ti = 0, a0 = 0;
  while (a0 + ti + 1 <= p){ a0 += ti + 1; ti++; }
  int tj = p - a0;
  int i0 = ti*64, j0 = tj*64;
  if (i0 >= K) return;
  __shared__ __align__(16) float As[16][68];
  __shared__ __align__(16) float Bs[16][68];
  int t = threadIdx.x;
  int lr = t >> 2, lk = (t & 3)*4;
  int ty = t >> 4, tx = t & 15;
  float acc[4][4] = {};
  for (int k0 = 0; k0 < MM; k0 += 16){
    int ri = i0 + lr, rj = j0 + lr;
    float4 zr = {0,0,0,0};
    float4 av = (ri < K) ? *(const float4*)(CT + ((size_t)b*K + ri)*MM + k0 + lk) : zr;
    float4 bv = (rj < K) ? *(const float4*)(CT + ((size_t)b*K + rj)*MM + k0 + lk) : zr;
    __syncthreads();
    As[lk+0][lr] = av.x; As[lk+1][lr] = av.y; As[lk+2][lr] = av.z; As[lk+3][lr] = av.w;
    Bs[lk+0][lr] = bv.x; Bs[lk+1][lr] = bv.y; Bs[lk+2][lr] = bv.z; Bs[lk+3][lr] = bv.w;
    __syncthreads();
    #pragma unroll
    for (int kk = 0; kk < 16; kk++){
      float4 a4 = *(const float4*)&As[kk][ty*4];
      float4 b4 = *(const float4*)&Bs[kk][tx*4];
      acc[0][0] += a4.x*b4.x; acc[0][1] += a4.x*b4.y; acc[0][2] += a4.x*b4.z; acc[0][3] += a4.x*b4.w;
      acc[1][0] += a4.y*b4.x; acc[1][1] += a4.y*b4.y; acc[1][2] += a4.y*b4.z; acc[1][3] += a4.y*b4.w;
      acc[2][0] += a4.z*b4.x; acc[2][1] += a4.z*b4.y; acc[2][2] += a4.z*b4.z; acc[2][3] += a4.z*b4.w;
      acc[3][0] += a4.w*b4.x; acc[3][1] += a4.w*b4.y; acc[3][2] += a4.w*b4.z; acc[3][3] += a4.w*b4.w;
    }
  }
  #pragma unroll
  for (int ii = 0; ii < 4; ii++)
  #pragma unroll
  for (int jj = 0; jj < 4; jj++){
    int i = i0 + ty*4 + ii, j = j0 + tx*4 + jj;
    if (i < K && j < K){
      float v = 0.5f*acc[ii][jj];
      G[((size_t)b*KP + i)*KP + j] = v;
      if (i0 != j0) G[((size_t)b*KP + j)*KP + i] = v;
    }
  }
}

// ---------------- the 100x loop: d = relu(wp)-2relu(wc); D = 0.5D + d; wn = base + 0.5wc - G d ----
__global__ __launch_bounds__(256) void k_iter(const float* __restrict__ G, const float* __restrict__ base,
    const float* __restrict__ wprev, const float* __restrict__ wcur, float* __restrict__ wnext,
    float* __restrict__ Da, const int* __restrict__ Kd){
  int K = Kd[0];
  int KP = (K + 3) & ~3;
  int b = blockIdx.y;
  int r0 = blockIdx.x * 128;
  if (r0 >= K) return;
  __shared__ __align__(16) float dl[KROWS];
  int t = threadIdx.x;
  const float* wp = wprev + (size_t)b*KROWS;
  const float* wc = wcur  + (size_t)b*KROWS;
  bool dBlk = (blockIdx.x == 0);
  for (int j = t; j < KP; j += 256){
    float d = 0.f;
    if (j < K){
      d = fmaxf(wp[j], 0.f) - 2.f*fmaxf(wc[j], 0.f);
      if (dBlk){ float* Db = Da + (size_t)b*KROWS; Db[j] = 0.5f*Db[j] + d; }
    }
    dl[j] = d;
  }
  __syncthreads();
  int lane = t & 63, wv = t >> 6;
  const float* Gb = G + (size_t)b*KP*KP;
  int rend = min(r0 + 128, K);
  for (int r = r0 + wv; r < rend; r += 4){
    const float* Gr = Gb + (size_t)r*KP;
    float acc = 0.f;
    for (int j = lane*4; j < KP; j += 256){
      float4 g = *(const float4*)(Gr + j);
      float4 dv = *(const float4*)(dl + j);
      acc += g.x*dv.x + g.y*dv.y + g.z*dv.z + g.w*dv.w;
    }
    for (int s = 32; s; s >>= 1) acc += __shfl_xor(acc, s);
    if (lane == 0) wnext[(size_t)b*KROWS + r] = base[(size_t)b*KROWS + r] + 0.5f*wc[r] - acc;
  }
}

// ---------------- psi = 2h + beta + 0.5 * L^{-T} (C^T^T . D) ----------------
__global__ __launch_bounds__(256) void k_mphi(const float* __restrict__ CT, const float* __restrict__ Lg,
    const float* __restrict__ Di, const float* __restrict__ Da, const float* __restrict__ hg,
    const float* __restrict__ bg, const int* __restrict__ Kd, float* __restrict__ psi){
  int K = Kd[0];
  int b = blockIdx.x, t = threadIdx.x;
  __shared__ float Dl[KCAP];
  __shared__ float mv[MM], yv[MM], u[16], pp[16][17];
  for (int j = t; j < K; j += 256) Dl[j] = Da[(size_t)b*KROWS + j];
  __syncthreads();
  float acc = 0.f;
  for (int j = 0; j < K; j++) acc += CT[((size_t)b*K + j)*MM + t] * Dl[j];
  mv[t] = acc;
  __syncthreads();
  solve_bwd(Lg + (size_t)b*LTOT, Di + (size_t)b*4096, mv, yv, u, pp, t);
  psi[b*MM + t] = 2.f*hg[b*MM + t] + bg[b*MM + t] + 0.5f*yv[t];
}

// ---------------- out: masked -> w100 - relu(w99); unmasked -> x - A^T psi ----------------
__global__ __launch_bounds__(256) void k_out(const float* __restrict__ A, const float* __restrict__ x,
    const float* __restrict__ psi, const int* __restrict__ pos, const float* __restrict__ w100,
    const float* __restrict__ w99, float* __restrict__ out){
  int b = blockIdx.x, t = threadIdx.x;
  __shared__ float ps[MM];
  ps[t] = psi[b*MM + t];
  __syncthreads();
  const float* Ab = A + (size_t)b*MM*VV;
  float4 acc = {0,0,0,0};
  for (int m = 0; m < MM; m++){
    float4 av = ((const float4*)(Ab + (size_t)m*VV))[t];
    float pm = ps[m];
    acc.x += av.x*pm; acc.y += av.y*pm; acc.z += av.z*pm; acc.w += av.w*pm;
  }
  float yv[4] = {acc.x, acc.y, acc.z, acc.w};
  float o[4];
  int v0 = t*4;
  #pragma unroll
  for (int c = 0; c < 4; c++){
    int v = v0 + c;
    int p = pos[v];
    if (p >= 0){
      float wN = w100[(size_t)b*KROWS + p];
      float wP = w99[(size_t)b*KROWS + p];
      o[c] = wN - fmaxf(wP, 0.f);
    } else {
      o[c] = x[(size_t)b*VV + v] - yv[c];
    }
  }
  float4 ov; ov.x = o[0]; ov.y = o[1]; ov.z = o[2]; ov.w = o[3];
  ((float4*)(out + (size_t)b*VV))[t] = ov;
}

extern "C" void kernel_launch(void* const* d_in, const int* in_sizes, int n_in,
                              void* d_out, int out_size, void* d_ws, size_t ws_size,
                              hipStream_t stream){
  const float* x    = (const float*)d_in[0];
  const float* bvec = (const float*)d_in[1];
  const float* A    = (const float*)d_in[2];
  const int*   mask = (const int*)d_in[3];
  float* out = (float*)d_out;
  if (ws_size < WS_NEED) return;   // signals workspace shortfall as "incorrect"
  char* w = (char*)d_ws;
  float* CT  = (float*)(w + CT_OFF);
  float* G   = (float*)(w + G_OFF);
  float* S   = (float*)(w + S_OFF);
  float* Lg  = (float*)(w + L_OFF);
  float* Di  = (float*)(w + DI_OFF);
  int*   idx = (int*)(w + IDX_OFF);
  int*   pos = (int*)(w + POS_OFF);
  int*   Kd  = (int*)(w + KD_OFF);
  float* ax  = (float*)(w + AX_OFF);
  float* hg  = (float*)(w + H_OFF);
  float* be  = (float*)(w + BE_OFF);
  float* psi = (float*)(w + PS_OFF);
  float* eh  = (float*)(w + EH_OFF);
  float* eb  = (float*)(w + EB_OFF);
  float* base= (float*)(w + BASE_OFF);
  float* P[3] = {(float*)(w + P0_OFF), (float*)(w + P1_OFF), (float*)(w + P2_OFF)};
  float* Da  = (float*)(w + DA_OFF);

  k_scan<<<1, 1024, 0, stream>>>(mask, idx, pos, Kd);
  k_ax  <<<BB, 256, 0, stream>>>(A, x, ax);
  k_aat <<<BB*10, 256, 0, stream>>>(A, S);
  k_chol<<<BB, 256, 0, stream>>>(S, Lg);
  k_dinv<<<BB, 256, 0, stream>>>(Lg, Di);
  k_small<<<BB, 256, 0, stream>>>(Lg, Di, S, ax, bvec, hg, be);
  k_e   <<<BB, 256, 0, stream>>>(A, hg, be, eh, eb);
  k_init<<<BB, 256, 0, stream>>>(x, eh, eb, idx, Kd, base, P[0], P[2], Da);
  k_solveC<<<dim3(18, BB), 256, 0, stream>>>(A, Lg, Di, idx, Kd, CT);
  k_gram<<<BB*45, 256, 0, stream>>>(CT, Kd, G);
  for (int it = 0; it < NITERS; it++){
    k_iter<<<dim3(5, BB), 256, 0, stream>>>(G, base, P[(it+2)%3], P[it%3], P[(it+1)%3], Da, Kd);
  }
  k_mphi<<<BB, 256, 0, stream>>>(CT, Lg, Di, Da, hg, be, Kd, psi);
  k_out <<<BB, 256, 0, stream>>>(A, x, psi, pos, P[NITERS%3], P[(NITERS-1)%3], out);
}